// Round 2
// baseline (2941.408 us; speedup 1.0000x reference)
//
#include <hip/hip_runtime.h>
#include <hip/hip_bf16.h>
#include <hip/hip_fp16.h>

// ---------------------------------------------------------------------------
// 3-layer GRU (Keras v2, reset_after=True), B=64 T=2048 F=H=128, OUT=5.
// Round 8: BATCH-PAIR ILP inside the r6 layer-pipelined persistent kernel.
//   Post-mortem r7 (wave-specialized producer/consumer): REGRESSED 1752->2038.
//   VALUBusy fell 44->36% -> the per-step stall is LOCKSTEP-PHASE latency
//   (all waves in the same serial chain simultaneously), not projection
//   serialization. r6's inline projection was already bubble-filling.
//   => back to the r6 single-role structure; each WG now owns TWO batches.
//   Recurrent+input weights are per-layer => shared (0 extra VGPRs); only
//   state (h, xw, accs, staging regs) duplicates (~20 VGPRs). The two
//   independent per-batch chains interleave in-thread: batch B's issue hides
//   batch A's chain latency and vice versa. No new synchronization.
//   Grid: 96 WGs = 3 layers x 32 pairs, 512 thr (8 waves, 2/SIMD).
//   Handoff: identical protocol to r6 (global f16 h-planes, per-(layer,pair)
//   flags, agent-scope release/acquire, CHK=16 chunks, producers never wait).
// ws: 3 h-planes f16 (~33.5MB each) + flags.
// ---------------------------------------------------------------------------

#define HID   128
#define H3    384
#define OUTD  5
#define CHK   16            // steps per chunk (publish/poll granularity)

typedef _Float16 f16x2 __attribute__((ext_vector_type(2)));
typedef _Float16 f16x8 __attribute__((ext_vector_type(8)));

__device__ __forceinline__ float fdot2(f16x2 a, f16x2 b, float c) {
#if __has_builtin(__builtin_amdgcn_fdot2)
    return __builtin_amdgcn_fdot2(a, b, c, false);   // v_dot2_f32_f16
#else
    return fmaf((float)a.x, (float)b.x, fmaf((float)a.y, (float)b.y, c));
#endif
}

__device__ __forceinline__ float fexp2(float x) {
#if __has_builtin(__builtin_amdgcn_exp2f)
    return __builtin_amdgcn_exp2f(x);
#else
    return exp2f(x);
#endif
}

__device__ __forceinline__ float frcp(float x) {
#if __has_builtin(__builtin_amdgcn_rcpf)
    return __builtin_amdgcn_rcpf(x);
#else
    return 1.f / x;
#endif
}

// sigmoid(x) = 1/(1+exp(-x)); saturates correctly at +-inf.
__device__ __forceinline__ float fsigmoid(float x) {
    return frcp(1.f + fexp2(x * -1.4426950408889634f));
}

// tanh(x) = 1 - 2/(1+exp(2x)); saturates correctly at +-inf.
__device__ __forceinline__ float ftanh_(float x) {
    return fmaf(-2.f, frcp(1.f + fexp2(x * 2.8853900817779268f)), 1.f);
}

// barrier that does NOT drain vmcnt (unlike __syncthreads): LDS handoff only.
__device__ __forceinline__ void soft_barrier() {
    asm volatile("s_waitcnt lgkmcnt(0)\n\ts_barrier" ::: "memory");
}

// butterfly sum over the kh quad (lanes xor 1, xor 2) on the VALU pipe
__device__ __forceinline__ float quad_sum(float x) {
#if __has_builtin(__builtin_amdgcn_mov_dpp)
    int i1 = __builtin_amdgcn_mov_dpp(__float_as_int(x), 0xB1, 0xF, 0xF, true); // [1,0,3,2]
    x += __int_as_float(i1);
    int i2 = __builtin_amdgcn_mov_dpp(__float_as_int(x), 0x4E, 0xF, 0xF, true); // [2,3,0,1]
    x += __int_as_float(i2);
#else
    x += __shfl_xor(x, 1);
    x += __shfl_xor(x, 2);
#endif
    return x;
}

// ---------------------------------------------------------------------------
__global__ void zero_flags(int* f) {
    if (threadIdx.x < 96) f[threadIdx.x] = 0;
}

// ---------------------------------------------------------------------------
// gru_pipe: 96 WGs = 3 layers x 32 batch-pairs, 512 thr (8 waves, 2/SIMD).
// Thread (j = t>>2, kh = t&3): unit j, k-quarter kh, for BOTH batches of the
// pair. Per step, per batch:
//   recurrent dot (48 fdot2, 16-deep) from LDS h dbuf -> DPP quad reduce
//   -> gates -> h update -> LDS+global store; inline input projection for
//   step t+1 (48 fdot2 from staged input row). The two batches' streams are
//   independent -> in-thread ILP fills each other's latency bubbles.
// ---------------------------------------------------------------------------
__global__ __launch_bounds__(512, 2) void gru_pipe(
    const float* __restrict__ x,                         // [64,T,128] fp32
    const float* __restrict__ k0, const float* __restrict__ k1, const float* __restrict__ k2,
    const float* __restrict__ rk0, const float* __restrict__ rk1, const float* __restrict__ rk2,
    const float* __restrict__ b0, const float* __restrict__ b1, const float* __restrict__ b2,
    _Float16* __restrict__ hpl0, _Float16* __restrict__ hpl1, _Float16* __restrict__ hpl2,
    int* flags, int T)
{
    const int blk   = blockIdx.x;
    const int layer = blk >> 5;       // 0..2
    const int pair  = blk & 31;       // batch pair
    const int bA    = pair * 2;
    const int bB    = bA + 1;
    const int t     = threadIdx.x;    // 0..511
    const int j     = t >> 2;         // unit 0..127
    const int kh    = t & 3;          // k-quarter
    const int k0i   = kh * 32;
    const int NC    = T / CHK;        // 128 chunks

    const float* Kw = (layer == 0) ? k0  : (layer == 1) ? k1  : k2;
    const float* Rw = (layer == 0) ? rk0 : (layer == 1) ? rk1 : rk2;
    const float* Bs = (layer == 0) ? b0  : (layer == 1) ? b1  : b2;
    const _Float16* hin = (layer == 1) ? hpl0 : hpl1;    // unused for layer 0
    _Float16* hout = (layer == 0) ? hpl0 : (layer == 1) ? hpl1 : hpl2;

    __shared__ __align__(16) _Float16 hb[2][2][HID];         // [bat][dbuf][unit]
    __shared__ __align__(16) _Float16 ins[2][2][CHK][HID];   // [slot][bat][row][col]

    // resident weights: recurrent + input, shared by both batches.
    // 3 gates x 16 f16x2 each x 2 (R,K) = 96 VGPRs
    f16x2 wzR[16], wrR[16], whR[16], wzK[16], wrK[16], whK[16];
#pragma unroll
    for (int p = 0; p < 16; ++p) {
        const int k = k0i + 2 * p;
        const float* r0p = Rw + (size_t)k * H3;
        const float* r1p = r0p + H3;
        const float* k0p = Kw + (size_t)k * H3;
        const float* k1p = k0p + H3;
        f16x2 a;
        a.x = (_Float16)r0p[j];       a.y = (_Float16)r1p[j];       wzR[p] = a;
        a.x = (_Float16)r0p[j + 128]; a.y = (_Float16)r1p[j + 128]; wrR[p] = a;
        a.x = (_Float16)r0p[j + 256]; a.y = (_Float16)r1p[j + 256]; whR[p] = a;
        a.x = (_Float16)k0p[j];       a.y = (_Float16)k1p[j];       wzK[p] = a;
        a.x = (_Float16)k0p[j + 128]; a.y = (_Float16)k1p[j + 128]; wrK[p] = a;
        a.x = (_Float16)k0p[j + 256]; a.y = (_Float16)k1p[j + 256]; whK[p] = a;
    }
    const float bzK = Bs[j]       + Bs[H3 + j];          // b_in(z)+b_rec(z)
    const float brK = Bs[128 + j] + Bs[H3 + 128 + j];    // b_in(r)+b_rec(r)
    const float bhK = Bs[256 + j];                       // b_in(h)
    const float bhR = Bs[H3 + 256 + j];                  // b_rec(h) (inside r*)

    int* myflag = flags + layer * 32 + pair;
    int* sflag  = flags + (layer - 1) * 32 + pair;

    const float*    xbA  = x    + (size_t)bA * T * HID;
    const float*    xbB  = x    + (size_t)bB * T * HID;
    const _Float16* hibA = hin  + (size_t)bA * T * HID;
    const _Float16* hibB = hin  + (size_t)bB * T * HID;
    _Float16*       hobA = hout + (size_t)bA * T * HID;
    _Float16*       hobB = hout + (size_t)bB * T * HID;

    // ---- staging: per batch, chunk = CHK rows x 128 f16 = 1024 f16x2 dwords
    // thread handles 2 dwords per batch: d = t + 512*i -> row = d>>6, col2 = d&63.
    f16x2 sregA[2], sregB[2];
    auto stage_load = [&](int cc) {
#pragma unroll
        for (int i = 0; i < 2; ++i) {
            const int d  = t + 512 * i;
            const int rw = d >> 6;
            const int c2 = d & 63;
            const size_t off = (size_t)(cc * CHK + rw) * HID + 2 * c2;
            if (layer == 0) {
                const float2 vA = *(const float2*)(xbA + off);
                const float2 vB = *(const float2*)(xbB + off);
                f16x2 oA; oA.x = (_Float16)vA.x; oA.y = (_Float16)vA.y;
                f16x2 oB; oB.x = (_Float16)vB.x; oB.y = (_Float16)vB.y;
                sregA[i] = oA; sregB[i] = oB;
            } else {
                sregA[i] = *(const f16x2*)(hibA + off);
                sregB[i] = *(const f16x2*)(hibB + off);
            }
        }
    };
    auto stage_write = [&](int cc) {
        const int slot = cc & 1;
#pragma unroll
        for (int i = 0; i < 2; ++i) {
            const int d  = t + 512 * i;
            const int rw = d >> 6;
            const int c2 = d & 63;
            *(f16x2*)(&ins[slot][0][rw][2 * c2]) = sregA[i];
            *(f16x2*)(&ins[slot][1][rw][2 * c2]) = sregB[i];
        }
    };
    // inline input projection for step tn, one batch (bat = 0/1)
    auto proj_one = [&](int tn, int bat, float& oz, float& orr, float& oh) {
        const f16x8* ip = (const f16x8*)(&ins[(tn >> 4) & 1][bat][tn & 15][k0i]);
        float pz = 0.f, pr = 0.f, ph = 0.f;
#pragma unroll
        for (int i = 0; i < 4; ++i) {
            union { f16x8 v; f16x2 p[4]; } u;
            u.v = ip[i];
#pragma unroll
            for (int q = 0; q < 4; ++q) {
                pz = fdot2(u.p[q], wzK[4 * i + q], pz);
                pr = fdot2(u.p[q], wrK[4 * i + q], pr);
                ph = fdot2(u.p[q], whK[4 * i + q], ph);
            }
        }
        oz = quad_sum(pz) + bzK;
        orr = quad_sum(pr) + brK;
        oh = quad_sum(ph) + bhK;
    };

    if (t < HID) {
        hb[0][0][t] = (_Float16)0.f; hb[0][1][t] = (_Float16)0.f;
        hb[1][0][t] = (_Float16)0.f; hb[1][1][t] = (_Float16)0.f;
    }

    // ---- prologue: chunk 0 staged + proj[0] ----
    if (layer > 0 && t == 0) {
        while (__hip_atomic_load(sflag, __ATOMIC_ACQUIRE, __HIP_MEMORY_SCOPE_AGENT) < CHK)
            __builtin_amdgcn_s_sleep(4);
    }
    __syncthreads();
    stage_load(0);
    stage_write(0);      // vmcnt wait here (prologue only)
    __syncthreads();

    float xzA, xrA, xhA, xzB, xrB, xhB;
    proj_one(0, 0, xzA, xrA, xhA);
    proj_one(0, 1, xzB, xrB, xhB);

    float hoA = 0.f, hoB = 0.f;

    // ---- main loop over chunks ----
    for (int c = 0; c < NC; ++c) {
        __syncthreads();   // drains vm+lgkm (h stores of prev chunk complete)
        if (t == 0) {
            if (layer < 2 && c > 0)
                __hip_atomic_store(myflag, c * CHK, __ATOMIC_RELEASE, __HIP_MEMORY_SCOPE_AGENT);
            if (layer > 0 && c + 1 < NC) {
                while (__hip_atomic_load(sflag, __ATOMIC_ACQUIRE, __HIP_MEMORY_SCOPE_AGENT) < (c + 2) * CHK)
                    __builtin_amdgcn_s_sleep(4);
            }
        }
        __syncthreads();
        if (c + 1 < NC) stage_load(c + 1);   // loads in flight ~8 steps before ds_write

#pragma unroll 2
        for (int ts = 0; ts < CHK; ++ts) {
            const int tstep = c * CHK + ts;
            const int rbuf  = ts & 1;

            // recurrent dots, both batches interleaved (independent chains)
            const f16x8* hpA = (const f16x8*)(&hb[0][rbuf][k0i]);
            const f16x8* hpB = (const f16x8*)(&hb[1][rbuf][k0i]);
            float szA = 0.f, srA = 0.f, shA = 0.f;
            float szB = 0.f, srB = 0.f, shB = 0.f;
#pragma unroll
            for (int i = 0; i < 4; ++i) {
                union { f16x8 v; f16x2 p[4]; } uA, uB;
                uA.v = hpA[i];
                uB.v = hpB[i];
#pragma unroll
                for (int q = 0; q < 4; ++q) {
                    szA = fdot2(uA.p[q], wzR[4 * i + q], szA);
                    szB = fdot2(uB.p[q], wzR[4 * i + q], szB);
                    srA = fdot2(uA.p[q], wrR[4 * i + q], srA);
                    srB = fdot2(uB.p[q], wrR[4 * i + q], srB);
                    shA = fdot2(uA.p[q], whR[4 * i + q], shA);
                    shB = fdot2(uB.p[q], whR[4 * i + q], shB);
                }
            }
            szA = quad_sum(szA); szB = quad_sum(szB);
            srA = quad_sum(srA); srB = quad_sum(srB);
            shA = quad_sum(shA); shB = quad_sum(shB);

            const float zA  = fsigmoid(xzA + szA);
            const float zB  = fsigmoid(xzB + szB);
            const float rA  = fsigmoid(xrA + srA);
            const float rB  = fsigmoid(xrB + srB);
            const float hhA = ftanh_(xhA + (shA + bhR) * rA);
            const float hhB = ftanh_(xhB + (shB + bhR) * rB);
            const float hnA = fmaf(zA, hoA - hhA, hhA);
            const float hnB = fmaf(zB, hoB - hhB, hhB);
            hoA = hnA; hoB = hnB;

            if (kh == 0) {
                hb[0][rbuf ^ 1][j] = (_Float16)hnA;
                hb[1][rbuf ^ 1][j] = (_Float16)hnB;
                hobA[(size_t)tstep * HID + j] = (_Float16)hnA;
                hobB[(size_t)tstep * HID + j] = (_Float16)hnB;
            }

            if (ts == 7 && c + 1 < NC) stage_write(c + 1);  // vmcnt hidden (~8 steps old)

            // inline input projection for step t+1, both batches
            if (tstep + 1 < T) {
                proj_one(tstep + 1, 0, xzA, xrA, xhA);
                proj_one(tstep + 1, 1, xzB, xrB, xhB);
            }

            soft_barrier();   // lgkm-only: global loads/stores stay in flight
        }
    }

    // final publish
    __syncthreads();
    if (t == 0 && layer < 2)
        __hip_atomic_store(myflag, T, __ATOMIC_RELEASE, __HIP_MEMORY_SCOPE_AGENT);
}

// ---------------------------------------------------------------------------
// out_proj: out[r,:] = h_f16[r,:] @ wo + bo (fp32 out). Thread = row.
// ---------------------------------------------------------------------------
__global__ __launch_bounds__(256) void out_proj(
    const _Float16* __restrict__ Hf,  // [R,128] f16
    const float* __restrict__ wo,     // [128,5]
    const float* __restrict__ bo,     // [5]
    float*       __restrict__ out,    // [R,5]
    int R)
{
    const int r = blockIdx.x * 256 + threadIdx.x;
    if (r >= R) return;
    const f16x8* xp = (const f16x8*)(Hf + (size_t)r * HID);

    float a0 = bo[0], a1 = bo[1], a2 = bo[2], a3 = bo[3], a4 = bo[4];
#pragma unroll 4
    for (int c = 0; c < 16; ++c) {
        const f16x8 v = xp[c];
#pragma unroll
        for (int e = 0; e < 8; ++e) {
            const float xv = (float)v[e];
            const float* w = wo + (size_t)(8 * c + e) * OUTD;
            a0 = fmaf(xv, w[0], a0);
            a1 = fmaf(xv, w[1], a1);
            a2 = fmaf(xv, w[2], a2);
            a3 = fmaf(xv, w[3], a3);
            a4 = fmaf(xv, w[4], a4);
        }
    }
    float* op = out + (size_t)r * OUTD;
    op[0] = a0; op[1] = a1; op[2] = a2; op[3] = a3; op[4] = a4;
}

// ---------------------------------------------------------------------------
extern "C" void kernel_launch(void* const* d_in, const int* in_sizes, int n_in,
                              void* d_out, int out_size, void* d_ws, size_t ws_size,
                              hipStream_t stream) {
    const float* x   = (const float*)d_in[0];
    const float* k0  = (const float*)d_in[1];
    const float* rk0 = (const float*)d_in[2];
    const float* b0  = (const float*)d_in[3];
    const float* k1  = (const float*)d_in[4];
    const float* rk1 = (const float*)d_in[5];
    const float* b1  = (const float*)d_in[6];
    const float* k2  = (const float*)d_in[7];
    const float* rk2 = (const float*)d_in[8];
    const float* b2  = (const float*)d_in[9];
    const float* wo  = (const float*)d_in[10];
    const float* bo  = (const float*)d_in[11];
    float* out = (float*)d_out;

    const int BT = in_sizes[0] / HID;   // 64*2048 = 131072 rows
    const int B  = 64;
    const int T  = BT / B;              // 2048

    // ws layout: 3 f16 h-planes + flags
    const size_t plane = (size_t)BT * HID * sizeof(_Float16);
    _Float16* hpl0 = (_Float16*)d_ws;
    _Float16* hpl1 = (_Float16*)((char*)d_ws + plane);
    _Float16* hpl2 = (_Float16*)((char*)d_ws + 2 * plane);
    int*      flags = (int*)((char*)d_ws + 3 * plane);

    zero_flags<<<1, 96, 0, stream>>>(flags);
    gru_pipe  <<<96, 512, 0, stream>>>(x, k0, k1, k2, rk0, rk1, rk2,
                                       b0, b1, b2, hpl0, hpl1, hpl2, flags, T);
    out_proj  <<<(BT + 255) / 256, 256, 0, stream>>>(hpl2, wo, bo, out, BT);
}